// Round 8
// baseline (295.423 us; speedup 1.0000x reference)
//
#include <hip/hip_runtime.h>
#include <hip/hip_bf16.h>
#include <math.h>

typedef __bf16 bf16_t;
typedef __bf16 bf16x8 __attribute__((ext_vector_type(8)));
typedef __bf16 bf16x4 __attribute__((ext_vector_type(4)));
typedef float  f32x4  __attribute__((ext_vector_type(4)));

#define D_MODEL 1024
#define NH      16
#define HD      64
#define BATCH   2
#define SEQ     2048
#define MROWS   (BATCH*SEQ)   // 4096
#define QKVN    (3*D_MODEL)   // 3072
#define FA_PAD  72            // LDS row stride: frag b128 reads at wave64 structural min
#define SCALE_LOG2E 0.18033688011112042f   // 0.125 * log2(e)

__device__ __forceinline__ void async_cp16(const bf16_t* g, bf16_t* l) {
    __builtin_amdgcn_global_load_lds(
        (const __attribute__((address_space(1))) void*)g,
        (__attribute__((address_space(3))) void*)l,
        16, 0, 0);
}

// ---------------- fp32 -> bf16 convert, all three inputs in one launch ------
__global__ void cvt_all(const float* __restrict__ x, const float* __restrict__ wq,
                        const float* __restrict__ wo,
                        bf16_t* __restrict__ xb, bf16_t* __restrict__ wqb,
                        bf16_t* __restrict__ wob) {
    const int nx = MROWS * D_MODEL, nq = QKVN * D_MODEL;
    int i = (blockIdx.x * blockDim.x + threadIdx.x) * 4;
    const float* s; bf16_t* d; int off;
    if (i < nx)           { s = x;  d = xb;  off = i; }
    else if (i < nx + nq) { s = wq; d = wqb; off = i - nx; }
    else                  { s = wo; d = wob; off = i - nx - nq; }
    float4 v = *(const float4*)(s + off);
    d[off]     = (bf16_t)v.x;
    d[off + 1] = (bf16_t)v.y;
    d[off + 2] = (bf16_t)v.z;
    d[off + 3] = (bf16_t)v.w;
}

// ---------------- QKV GEMM (BK=64) with fused RoPE + head-split epilogue ----
// C = x @ w_qkv^T (M=4096, N=3072, K=1024). Instead of materializing qkv,
// the epilogue applies RoPE to Q/K (feature pairs sit in adjacent lanes ->
// one shfl_xor) and writes Qh/Kh [bh][s][d] and VT [bh][d][s] directly.
__global__ __launch_bounds__(256) void gemm_qkv_rope(const bf16_t* __restrict__ A,
                                                     const bf16_t* __restrict__ Bm,
                                                     const int* __restrict__ pos,
                                                     bf16_t* __restrict__ Qh,
                                                     bf16_t* __restrict__ Kh,
                                                     bf16_t* __restrict__ VT) {
    const int K = D_MODEL, N = QKVN;
    __shared__ __align__(16) bf16_t As[2][128 * 32];
    __shared__ __align__(16) bf16_t Bs[2][128 * 32];
    const int tid  = threadIdx.x;
    const int w    = tid >> 6;
    const int lane = tid & 63;
    const int quad = lane >> 4;
    const int l16  = lane & 15;
    const int m0   = blockIdx.x * 128;
    const int n0   = blockIdx.y * 128;
    const int wm   = (w >> 1) * 64;
    const int wn   = (w & 1) * 64;

    f32x4 acc[4][4];
    #pragma unroll
    for (int i = 0; i < 4; i++)
        #pragma unroll
        for (int j = 0; j < 4; j++)
            acc[i][j] = (f32x4){0.f, 0.f, 0.f, 0.f};

    const bf16_t* Ag0 = A  + (size_t)(m0 + (tid >> 2)) * K + (tid & 3) * 8;
    const bf16_t* Ag1 = Ag0 + (size_t)64 * K;
    const bf16_t* Bg0 = Bm + (size_t)(n0 + (tid >> 2)) * K + (tid & 3) * 8;
    const bf16_t* Bg1 = Bg0 + (size_t)64 * K;

    for (int k0 = 0; k0 < K; k0 += 64) {
        #pragma unroll
        for (int kk = 0; kk < 2; kk++) {
            const int kc = k0 + kk * 32;
            async_cp16(Ag0 + kc, &As[kk][(size_t)tid * 8]);
            async_cp16(Ag1 + kc, &As[kk][((size_t)tid + 256) * 8]);
            async_cp16(Bg0 + kc, &Bs[kk][(size_t)tid * 8]);
            async_cp16(Bg1 + kc, &Bs[kk][((size_t)tid + 256) * 8]);
        }
        __syncthreads();

        #pragma unroll
        for (int kk = 0; kk < 2; kk++) {
            bf16x8 af[4], bfr[4];
            #pragma unroll
            for (int mi = 0; mi < 4; mi++)
                af[mi] = *(const bf16x8*)&As[kk][(wm + mi * 16 + l16) * 32 + quad * 8];
            #pragma unroll
            for (int ni = 0; ni < 4; ni++)
                bfr[ni] = *(const bf16x8*)&Bs[kk][(wn + ni * 16 + l16) * 32 + quad * 8];
            #pragma unroll
            for (int mi = 0; mi < 4; mi++)
                #pragma unroll
                for (int ni = 0; ni < 4; ni++)
                    acc[mi][ni] = __builtin_amdgcn_mfma_f32_16x16x32_bf16(
                        af[mi], bfr[ni], acc[mi][ni], 0, 0, 0);
        }
        __syncthreads();
    }

    // ---- fused epilogue: RoPE Q/K, direct head-split writes ----
    #pragma unroll
    for (int ni = 0; ni < 4; ni++) {
        const int col    = n0 + wn + ni * 16 + l16;
        const int region = col >> 10;          // 0=Q 1=K 2=V (wave-uniform per ni)
        const int c10    = col & 1023;
        const int h      = c10 >> 6;
        const int d      = c10 & 63;
        if (region < 2) {
            bf16_t* dst = region ? Kh : Qh;
            const int d2 = d >> 1;
            const float sgn = (col & 1) ? 1.f : -1.f;
            const float inv = __expf(-0.28782313662425575f * (float)d2);  // theta^(-d2/32)
            #pragma unroll
            for (int mi = 0; mi < 4; mi++) {
                #pragma unroll
                for (int r = 0; r < 4; r++) {
                    const int row = m0 + wm + mi * 16 + quad * 4 + r;
                    const int s = row & (SEQ - 1), bb = row >> 11;
                    const float f = (float)pos[s] * inv;
                    const float c = cosf(f), sn = sinf(f);
                    const float val  = acc[mi][ni][r];
                    const float pair = __shfl_xor(val, 1);
                    dst[((size_t)(bb * NH + h) * SEQ + s) * HD + d] =
                        (bf16_t)(val * c + sgn * pair * sn);
                }
            }
        } else {
            #pragma unroll
            for (int mi = 0; mi < 4; mi++) {
                #pragma unroll
                for (int r = 0; r < 4; r++) {
                    const int row = m0 + wm + mi * 16 + quad * 4 + r;
                    const int s = row & (SEQ - 1), bb = row >> 11;
                    VT[((size_t)(bb * NH + h) * HD + d) * SEQ + s] = (bf16_t)acc[mi][ni][r];
                }
            }
        }
    }
}

// ---------------- NT GEMM, BK=64 (out-projection) ---------------------------
template <typename OutT, int NI>
__global__ __launch_bounds__(256) void gemm_nt(const bf16_t* __restrict__ A,
                                               const bf16_t* __restrict__ Bm,
                                               OutT* __restrict__ C,
                                               int M, int N, int K) {
    __shared__ __align__(16) bf16_t As[2][128 * 32];
    __shared__ __align__(16) bf16_t Bs[2][NI * 32 * 32];
    const int tid  = threadIdx.x;
    const int w    = tid >> 6;
    const int lane = tid & 63;
    const int quad = lane >> 4;
    const int l16  = lane & 15;
    const int m0   = blockIdx.x * 128;
    const int n0   = blockIdx.y * (NI * 32);
    const int wm   = (w >> 1) * 64;
    const int wn   = (w & 1) * (NI * 16);

    f32x4 acc[4][NI];
    #pragma unroll
    for (int i = 0; i < 4; i++)
        #pragma unroll
        for (int j = 0; j < NI; j++)
            acc[i][j] = (f32x4){0.f, 0.f, 0.f, 0.f};

    const bf16_t* Ag0 = A  + (size_t)(m0 + (tid >> 2)) * K + (tid & 3) * 8;
    const bf16_t* Ag1 = Ag0 + (size_t)64 * K;
    const bf16_t* Bg0 = Bm + (size_t)(n0 + (tid >> 2)) * K + (tid & 3) * 8;
    const bf16_t* Bg1 = Bg0 + (size_t)64 * K;

    for (int k0 = 0; k0 < K; k0 += 64) {
        #pragma unroll
        for (int kk = 0; kk < 2; kk++) {
            const int kc = k0 + kk * 32;
            async_cp16(Ag0 + kc, &As[kk][(size_t)tid * 8]);
            async_cp16(Ag1 + kc, &As[kk][((size_t)tid + 256) * 8]);
            async_cp16(Bg0 + kc, &Bs[kk][(size_t)tid * 8]);
            if (NI == 4) async_cp16(Bg1 + kc, &Bs[kk][((size_t)tid + 256) * 8]);
        }
        __syncthreads();

        #pragma unroll
        for (int kk = 0; kk < 2; kk++) {
            bf16x8 af[4], bfr[NI];
            #pragma unroll
            for (int mi = 0; mi < 4; mi++)
                af[mi] = *(const bf16x8*)&As[kk][(wm + mi * 16 + l16) * 32 + quad * 8];
            #pragma unroll
            for (int ni = 0; ni < NI; ni++)
                bfr[ni] = *(const bf16x8*)&Bs[kk][(wn + ni * 16 + l16) * 32 + quad * 8];
            #pragma unroll
            for (int mi = 0; mi < 4; mi++)
                #pragma unroll
                for (int ni = 0; ni < NI; ni++)
                    acc[mi][ni] = __builtin_amdgcn_mfma_f32_16x16x32_bf16(
                        af[mi], bfr[ni], acc[mi][ni], 0, 0, 0);
        }
        __syncthreads();
    }

    #pragma unroll
    for (int mi = 0; mi < 4; mi++)
        #pragma unroll
        for (int ni = 0; ni < NI; ni++) {
            const int col = n0 + wn + ni * 16 + l16;
            #pragma unroll
            for (int r = 0; r < 4; r++) {
                const int row = m0 + wm + mi * 16 + quad * 4 + r;
                C[(size_t)row * N + col] = (OutT)acc[mi][ni][r];
            }
        }
}

// ---------------- causal flash attention: round-4 structure (proven) --------
// 512 thr = 8 waves: waves 0-3 big q-tile, 4-7 paired small tile; shared K/V
// staged in LDS, double-buffered, one barrier per iter; max-free softmax via
// S^T = K*Q^T (P lands transposed -> contiguous A-frag reads from LDS).
__global__ __launch_bounds__(512) void flash_attn(const bf16_t* __restrict__ Qh,
                                                  const bf16_t* __restrict__ Kh,
                                                  const bf16_t* __restrict__ VT,
                                                  bf16_t* __restrict__ AO) {
    __shared__ __align__(16) bf16_t Ks[2][64 * FA_PAD];    // [buf][kv][d]
    __shared__ __align__(16) bf16_t Vs[2][64 * FA_PAD];    // [buf][d][kv]
    __shared__ __align__(16) bf16_t pT[8][16][FA_PAD];     // per-wave [q][kv]

    const int tid  = threadIdx.x;
    const int w    = tid >> 6;
    const int lane = tid & 63;
    const int quad = lane >> 4;
    const int l16  = lane & 15;
    const int wq   = w & 3;        // wave's 16-row slice within its q-tile
    const int g    = w >> 2;       // 0 = big tile, 1 = small tile

    const int bid  = blockIdx.x;
    const int xcd  = bid & 7;
    const int mm   = bid >> 3;                 // 0..63
    const int bh   = (mm >> 4) * 8 + xcd;      // same-bh blocks share an XCD
    const int pair = mm & 15;                  // pair 0 (longest) dispatches first
    const int qt_big = 31 - pair;
    const int my_qt  = g ? pair : qt_big;
    const int niter  = qt_big + 1;             // 17..32

    const bf16_t* Qb = Qh + (size_t)bh * SEQ * HD;
    const bf16_t* Kb = Kh + (size_t)bh * SEQ * HD;
    const bf16_t* Vb = VT + (size_t)bh * HD * SEQ;

    const int q0 = my_qt * 64 + wq * 16;
    const bf16x8 aq0 = *(const bf16x8*)(Qb + (size_t)(q0 + l16) * HD + quad * 8);
    const bf16x8 aq1 = *(const bf16x8*)(Qb + (size_t)(q0 + l16) * HD + 32 + quad * 8);

    // staging: 512 threads, one b128 each for K and V
    const int srow = tid >> 3, scol = (tid & 7) * 8;
    const int lds_off = srow * FA_PAD + scol;

    f32x4 o[4];
    #pragma unroll
    for (int i = 0; i < 4; i++) o[i] = (f32x4){0.f, 0.f, 0.f, 0.f};
    float lsum = 0.f;

    // prologue: tile 0 -> buf 0
    bf16x8 pK = *(const bf16x8*)(Kb + (size_t)srow * HD + scol);
    bf16x8 pV = *(const bf16x8*)(Vb + (size_t)srow * SEQ + scol);
    *(bf16x8*)&Ks[0][lds_off] = pK;
    *(bf16x8*)&Vs[0][lds_off] = pV;

    for (int kt = 0; kt < niter; ++kt) {
        const int cur = kt & 1;
        // prefetch next tile before the barrier (spans barrier-wait + compute)
        if (kt + 1 < niter) {
            const int kn = (kt + 1) * 64;
            pK = *(const bf16x8*)(Kb + (size_t)(kn + srow) * HD + scol);
            pV = *(const bf16x8*)(Vb + (size_t)srow * SEQ + kn + scol);
        }
        __syncthreads();   // buf[cur] visible; everyone done reading buf[cur^1]

        if (kt <= my_qt) {
            const bool diag = (kt == my_qt);
            const bf16_t* KsC = &Ks[cur][0];
            const bf16_t* VsC = &Vs[cur][0];

            #pragma unroll
            for (int ni = 0; ni < 4; ni++) {
                if (diag && ni > wq) {   // fully-masked kv sub-tile
                    *(bf16x4*)&pT[w][l16][ni * 16 + quad * 4] = (bf16x4){0, 0, 0, 0};
                    continue;
                }
                bf16x8 kb0 = *(const bf16x8*)&KsC[(ni * 16 + l16) * FA_PAD + quad * 8];
                bf16x8 kb1 = *(const bf16x8*)&KsC[(ni * 16 + l16) * FA_PAD + 32 + quad * 8];
                f32x4 t = (f32x4){0.f, 0.f, 0.f, 0.f};
                t = __builtin_amdgcn_mfma_f32_16x16x32_bf16(kb0, aq0, t, 0, 0, 0);  // S^T
                t = __builtin_amdgcn_mfma_f32_16x16x32_bf16(kb1, aq1, t, 0, 0, 0);
                bf16x4 pk;
                #pragma unroll
                for (int r = 0; r < 4; r++) {
                    float pv = exp2f(t[r] * SCALE_LOG2E);
                    if (diag && (ni * 16 + quad * 4 + r > wq * 16 + l16)) pv = 0.f;
                    lsum += pv;
                    pk[r] = (bf16_t)pv;
                }
                *(bf16x4*)&pT[w][l16][ni * 16 + quad * 4] = pk;
            }

            // PV: pT is wave-private -> no barrier
            #pragma unroll
            for (int ks = 0; ks < 2; ks++) {
                if (diag && wq * 16 + 15 < ks * 32) continue;
                bf16x8 ap = *(const bf16x8*)&pT[w][l16][ks * 32 + quad * 8];
                #pragma unroll
                for (int ni = 0; ni < 4; ni++) {
                    bf16x8 vb = *(const bf16x8*)&VsC[(ni * 16 + l16) * FA_PAD + ks * 32 + quad * 8];
                    o[ni] = __builtin_amdgcn_mfma_f32_16x16x32_bf16(ap, vb, o[ni], 0, 0, 0);
                }
            }
        }

        if (kt + 1 < niter) {
            *(bf16x8*)&Ks[cur ^ 1][lds_off] = pK;
            *(bf16x8*)&Vs[cur ^ 1][lds_off] = pV;
        }
    }

    // finalize: reduce lsum over quads, redistribute to C-layout rows
    lsum += __shfl_xor(lsum, 16);
    lsum += __shfl_xor(lsum, 32);
    f32x4 linv;
    #pragma unroll
    for (int r = 0; r < 4; r++)
        linv[r] = 1.0f / __shfl(lsum, quad * 4 + r);

    const int b = bh >> 4, h = bh & 15;
    #pragma unroll
    for (int ni = 0; ni < 4; ni++) {
        #pragma unroll
        for (int r = 0; r < 4; r++) {
            const size_t row = (size_t)b * SEQ + q0 + quad * 4 + r;
            AO[row * D_MODEL + h * HD + ni * 16 + l16] = (bf16_t)(o[ni][r] * linv[r]);
        }
    }
}

// ---------------- launcher ----------------
extern "C" void kernel_launch(void* const* d_in, const int* in_sizes, int n_in,
                              void* d_out, int out_size, void* d_ws, size_t ws_size,
                              hipStream_t stream) {
    const float* x     = (const float*)d_in[0];
    const float* w_qkv = (const float*)d_in[1];
    const float* w_o   = (const float*)d_in[2];
    const int*   tpos  = (const int*)d_in[3];
    float*       out   = (float*)d_out;

    char* ws = (char*)d_ws;
    bf16_t* xb  = (bf16_t*)(ws);                 //  8 MB
    bf16_t* wqb = (bf16_t*)(ws + 8388608);       //  6 MB
    bf16_t* wob = (bf16_t*)(ws + 14680064);      //  2 MB
    bf16_t* Qh  = (bf16_t*)(ws + 41943040);      //  8 MB: Q heads rope  [32,2048,64]
    bf16_t* Kh  = (bf16_t*)(ws + 50331648);      //  8 MB: K heads rope  [32,2048,64]
    bf16_t* VT  = (bf16_t*)(ws + 58720256);      //  8 MB: V^T           [32,64,2048]
    bf16_t* AO  = (bf16_t*)(ws + 67108864);      //  8 MB: attn out      [4096,1024]

    cvt_all<<<8192, 256, 0, stream>>>(x, w_qkv, w_o, xb, wqb, wob);

    // qkv GEMM with fused RoPE/head-split/V-transpose epilogue
    gemm_qkv_rope<<<dim3(32, 24), 256, 0, stream>>>(xb, wqb, tpos, Qh, Kh, VT);

    flash_attn<<<512, 512, 0, stream>>>(Qh, Kh, VT, AO);

    // out = AO @ w_o^T : M=4096, N=1024, K=1024 (fp32 out)
    gemm_nt<float, 2><<<dim3(32, 16), 256, 0, stream>>>(AO, wob, out, MROWS, D_MODEL, D_MODEL);
}

// Round 9
// 286.136 us; speedup vs baseline: 1.0325x; 1.0325x over previous
//
#include <hip/hip_runtime.h>
#include <hip/hip_bf16.h>
#include <math.h>

typedef __bf16 bf16_t;
typedef __bf16 bf16x8 __attribute__((ext_vector_type(8)));
typedef __bf16 bf16x4 __attribute__((ext_vector_type(4)));
typedef float  f32x4  __attribute__((ext_vector_type(4)));

#define D_MODEL 1024
#define NH      16
#define HD      64
#define BATCH   2
#define SEQ     2048
#define MROWS   (BATCH*SEQ)   // 4096
#define QKVN    (3*D_MODEL)   // 3072
#define FA_PAD  72            // LDS row stride: frag b128 reads at wave64 structural min
#define T_PAD   136           // transpose-tile row stride (b128-aligned)
#define SCALE_LOG2E 0.18033688011112042f   // 0.125 * log2(e)

__device__ __forceinline__ void async_cp16(const bf16_t* g, bf16_t* l) {
    __builtin_amdgcn_global_load_lds(
        (const __attribute__((address_space(1))) void*)g,
        (__attribute__((address_space(3))) void*)l,
        16, 0, 0);
}

// ---------------- fp32 -> bf16 convert, all three inputs in one launch ------
__global__ void cvt_all(const float* __restrict__ x, const float* __restrict__ wq,
                        const float* __restrict__ wo,
                        bf16_t* __restrict__ xb, bf16_t* __restrict__ wqb,
                        bf16_t* __restrict__ wob) {
    const int nx = MROWS * D_MODEL, nq = QKVN * D_MODEL;
    int i = (blockIdx.x * blockDim.x + threadIdx.x) * 4;
    const float* s; bf16_t* d; int off;
    if (i < nx)           { s = x;  d = xb;  off = i; }
    else if (i < nx + nq) { s = wq; d = wqb; off = i - nx; }
    else                  { s = wo; d = wob; off = i - nx - nq; }
    float4 v = *(const float4*)(s + off);
    d[off]     = (bf16_t)v.x;
    d[off + 1] = (bf16_t)v.y;
    d[off + 2] = (bf16_t)v.z;
    d[off + 3] = (bf16_t)v.w;
}

// ---------------- QKV GEMM (BK=64) + fused RoPE/head-split epilogue ---------
// C = x @ w_qkv^T (M=4096, N=3072, K=1024). blockIdx.y: 0-7 -> Q, 8-15 -> K,
// 16-23 -> V (region uniform per block). Epilogue: Phase A ropes Q/K in
// registers (pairs in adjacent lanes -> shfl_xor) and stores the bf16 C-tile
// into an LDS transpose buffer (aliased over As/Bs); Phase B re-reads in
// output-major order and writes Qh/Kh/VT with 128B-contiguous segments
// (HBM-line-clean: round-8's 2B scatters caused 33x write amplification).
__global__ __launch_bounds__(256) void gemm_qkv_rope(const bf16_t* __restrict__ A,
                                                     const bf16_t* __restrict__ Bm,
                                                     const int* __restrict__ pos,
                                                     bf16_t* __restrict__ Qh,
                                                     bf16_t* __restrict__ Kh,
                                                     bf16_t* __restrict__ VT) {
    const int K = D_MODEL;
    // 32 KB staging (As0,As1,Bs0,Bs1) aliased with 34 KB transpose tile
    __shared__ __align__(16) char smem[128 * T_PAD * 2];
    bf16_t* As0 = (bf16_t*)smem;
    bf16_t* As1 = As0 + 4096;
    bf16_t* Bs0 = As0 + 8192;
    bf16_t* Bs1 = As0 + 12288;
    bf16_t (*Tt)[T_PAD] = (bf16_t(*)[T_PAD])smem;

    const int tid  = threadIdx.x;
    const int w    = tid >> 6;
    const int lane = tid & 63;
    const int quad = lane >> 4;
    const int l16  = lane & 15;
    const int m0   = blockIdx.x * 128;
    const int n0   = blockIdx.y * 128;
    const int wm   = (w >> 1) * 64;
    const int wn   = (w & 1) * 64;

    f32x4 acc[4][4];
    #pragma unroll
    for (int i = 0; i < 4; i++)
        #pragma unroll
        for (int j = 0; j < 4; j++)
            acc[i][j] = (f32x4){0.f, 0.f, 0.f, 0.f};

    const bf16_t* Ag0 = A  + (size_t)(m0 + (tid >> 2)) * K + (tid & 3) * 8;
    const bf16_t* Ag1 = Ag0 + (size_t)64 * K;
    const bf16_t* Bg0 = Bm + (size_t)(n0 + (tid >> 2)) * K + (tid & 3) * 8;
    const bf16_t* Bg1 = Bg0 + (size_t)64 * K;

    for (int k0 = 0; k0 < K; k0 += 64) {
        async_cp16(Ag0 + k0,      &As0[(size_t)tid * 8]);
        async_cp16(Ag1 + k0,      &As0[((size_t)tid + 256) * 8]);
        async_cp16(Bg0 + k0,      &Bs0[(size_t)tid * 8]);
        async_cp16(Bg1 + k0,      &Bs0[((size_t)tid + 256) * 8]);
        async_cp16(Ag0 + k0 + 32, &As1[(size_t)tid * 8]);
        async_cp16(Ag1 + k0 + 32, &As1[((size_t)tid + 256) * 8]);
        async_cp16(Bg0 + k0 + 32, &Bs1[(size_t)tid * 8]);
        async_cp16(Bg1 + k0 + 32, &Bs1[((size_t)tid + 256) * 8]);
        __syncthreads();

        #pragma unroll
        for (int kk = 0; kk < 2; kk++) {
            const bf16_t* Asc = kk ? As1 : As0;
            const bf16_t* Bsc = kk ? Bs1 : Bs0;
            bf16x8 af[4], bfr[4];
            #pragma unroll
            for (int mi = 0; mi < 4; mi++)
                af[mi] = *(const bf16x8*)&Asc[(wm + mi * 16 + l16) * 32 + quad * 8];
            #pragma unroll
            for (int ni = 0; ni < 4; ni++)
                bfr[ni] = *(const bf16x8*)&Bsc[(wn + ni * 16 + l16) * 32 + quad * 8];
            #pragma unroll
            for (int mi = 0; mi < 4; mi++)
                #pragma unroll
                for (int ni = 0; ni < 4; ni++)
                    acc[mi][ni] = __builtin_amdgcn_mfma_f32_16x16x32_bf16(
                        af[mi], bfr[ni], acc[mi][ni], 0, 0, 0);
        }
        __syncthreads();   // also fences the last tile before Tt aliasing
    }

    const int region = n0 >> 10;            // 0=Q 1=K 2=V (block-uniform)
    const int hbase  = (n0 & 1023) >> 6;
    const int bb     = m0 >> 11;
    const int s0     = m0 & 2047;

    // ---- Phase A: C-tile (rope'd for Q/K) -> LDS transpose buffer ----
    if (region < 2) {
        #pragma unroll
        for (int ni = 0; ni < 4; ni++) {
            const int lc  = wn + ni * 16 + l16;       // local col 0..127
            const int d   = (n0 + lc) & 63;
            const int d2  = d >> 1;
            const float sgn = (d & 1) ? 1.f : -1.f;
            const float inv = __expf(-0.28782313662425575f * (float)d2);  // theta^(-d2/32)
            #pragma unroll
            for (int mi = 0; mi < 4; mi++) {
                #pragma unroll
                for (int r = 0; r < 4; r++) {
                    const int lr = wm + mi * 16 + quad * 4 + r;  // local row 0..127
                    const int s  = (m0 + lr) & (SEQ - 1);
                    const float f = (float)pos[s] * inv;
                    const float c = cosf(f), sn = sinf(f);
                    const float val  = acc[mi][ni][r];
                    const float pair = __shfl_xor(val, 1);
                    Tt[lr][lc] = (bf16_t)(val * c + sgn * pair * sn);
                }
            }
        }
    } else {
        #pragma unroll
        for (int ni = 0; ni < 4; ni++) {
            const int lc = wn + ni * 16 + l16;
            #pragma unroll
            for (int mi = 0; mi < 4; mi++)
                #pragma unroll
                for (int r = 0; r < 4; r++)
                    Tt[wm + mi * 16 + quad * 4 + r][lc] = (bf16_t)acc[mi][ni][r];
        }
    }
    __syncthreads();

    // ---- Phase B: output-major coalesced writes (128B+ contiguous/group) ---
    if (region < 2) {
        bf16_t* dst = region ? Kh : Qh;
        const int c  = lane & 7;          // 16B chunk within a 128B row
        const int ps = lane >> 3;         // 8 rows per instruction
        #pragma unroll
        for (int it = 0; it < 8; it++) {
            const int p  = (w * 8 + it) * 8 + ps;     // 0..255 = 2h x 128s
            const int hl = p >> 7, sl = p & 127;
            bf16x8 v = *(const bf16x8*)&Tt[sl][hl * 64 + c * 8];
            *(bf16x8*)(dst + ((size_t)(bb * NH + hbase + hl) * SEQ + s0 + sl) * HD + c * 8) = v;
        }
    } else {
        const int c  = lane & 15;         // 16B chunk within a 256B row
        const int r4 = lane >> 4;         // 4 rows per instruction
        #pragma unroll
        for (int it = 0; it < 8; it++) {
            const int p  = (it * 4 + w) * 4 + r4;     // 0..127 = 2h x 64d
            const int hl = p >> 6, d = p & 63;
            bf16_t tmp[8];
            #pragma unroll
            for (int j = 0; j < 8; j++) tmp[j] = Tt[c * 8 + j][p];
            *(bf16x8*)(VT + ((size_t)(bb * NH + hbase + hl) * HD + d) * SEQ + s0 + c * 8) =
                *(bf16x8*)tmp;
        }
    }
}

// ---------------- NT GEMM, BK=64 (out-projection) ---------------------------
template <typename OutT, int NI>
__global__ __launch_bounds__(256) void gemm_nt(const bf16_t* __restrict__ A,
                                               const bf16_t* __restrict__ Bm,
                                               OutT* __restrict__ C,
                                               int M, int N, int K) {
    __shared__ __align__(16) bf16_t As[2][128 * 32];
    __shared__ __align__(16) bf16_t Bs[2][NI * 32 * 32];
    const int tid  = threadIdx.x;
    const int w    = tid >> 6;
    const int lane = tid & 63;
    const int quad = lane >> 4;
    const int l16  = lane & 15;
    const int m0   = blockIdx.x * 128;
    const int n0   = blockIdx.y * (NI * 32);
    const int wm   = (w >> 1) * 64;
    const int wn   = (w & 1) * (NI * 16);

    f32x4 acc[4][NI];
    #pragma unroll
    for (int i = 0; i < 4; i++)
        #pragma unroll
        for (int j = 0; j < NI; j++)
            acc[i][j] = (f32x4){0.f, 0.f, 0.f, 0.f};

    const bf16_t* Ag0 = A  + (size_t)(m0 + (tid >> 2)) * K + (tid & 3) * 8;
    const bf16_t* Ag1 = Ag0 + (size_t)64 * K;
    const bf16_t* Bg0 = Bm + (size_t)(n0 + (tid >> 2)) * K + (tid & 3) * 8;
    const bf16_t* Bg1 = Bg0 + (size_t)64 * K;

    for (int k0 = 0; k0 < K; k0 += 64) {
        #pragma unroll
        for (int kk = 0; kk < 2; kk++) {
            const int kc = k0 + kk * 32;
            async_cp16(Ag0 + kc, &As[kk][(size_t)tid * 8]);
            async_cp16(Ag1 + kc, &As[kk][((size_t)tid + 256) * 8]);
            async_cp16(Bg0 + kc, &Bs[kk][(size_t)tid * 8]);
            if (NI == 4) async_cp16(Bg1 + kc, &Bs[kk][((size_t)tid + 256) * 8]);
        }
        __syncthreads();

        #pragma unroll
        for (int kk = 0; kk < 2; kk++) {
            bf16x8 af[4], bfr[NI];
            #pragma unroll
            for (int mi = 0; mi < 4; mi++)
                af[mi] = *(const bf16x8*)&As[kk][(wm + mi * 16 + l16) * 32 + quad * 8];
            #pragma unroll
            for (int ni = 0; ni < NI; ni++)
                bfr[ni] = *(const bf16x8*)&Bs[kk][(wn + ni * 16 + l16) * 32 + quad * 8];
            #pragma unroll
            for (int mi = 0; mi < 4; mi++)
                #pragma unroll
                for (int ni = 0; ni < NI; ni++)
                    acc[mi][ni] = __builtin_amdgcn_mfma_f32_16x16x32_bf16(
                        af[mi], bfr[ni], acc[mi][ni], 0, 0, 0);
        }
        __syncthreads();
    }

    #pragma unroll
    for (int mi = 0; mi < 4; mi++)
        #pragma unroll
        for (int ni = 0; ni < NI; ni++) {
            const int col = n0 + wn + ni * 16 + l16;
            #pragma unroll
            for (int r = 0; r < 4; r++) {
                const int row = m0 + wm + mi * 16 + quad * 4 + r;
                C[(size_t)row * N + col] = (OutT)acc[mi][ni][r];
            }
        }
}

// ---------------- causal flash attention: round-4 structure (proven) --------
__global__ __launch_bounds__(512) void flash_attn(const bf16_t* __restrict__ Qh,
                                                  const bf16_t* __restrict__ Kh,
                                                  const bf16_t* __restrict__ VT,
                                                  bf16_t* __restrict__ AO) {
    __shared__ __align__(16) bf16_t Ks[2][64 * FA_PAD];    // [buf][kv][d]
    __shared__ __align__(16) bf16_t Vs[2][64 * FA_PAD];    // [buf][d][kv]
    __shared__ __align__(16) bf16_t pT[8][16][FA_PAD];     // per-wave [q][kv]

    const int tid  = threadIdx.x;
    const int w    = tid >> 6;
    const int lane = tid & 63;
    const int quad = lane >> 4;
    const int l16  = lane & 15;
    const int wq   = w & 3;        // wave's 16-row slice within its q-tile
    const int g    = w >> 2;       // 0 = big tile, 1 = small tile

    const int bid  = blockIdx.x;
    const int xcd  = bid & 7;
    const int mm   = bid >> 3;                 // 0..63
    const int bh   = (mm >> 4) * 8 + xcd;      // same-bh blocks share an XCD
    const int pair = mm & 15;                  // pair 0 (longest) dispatches first
    const int qt_big = 31 - pair;
    const int my_qt  = g ? pair : qt_big;
    const int niter  = qt_big + 1;             // 17..32

    const bf16_t* Qb = Qh + (size_t)bh * SEQ * HD;
    const bf16_t* Kb = Kh + (size_t)bh * SEQ * HD;
    const bf16_t* Vb = VT + (size_t)bh * HD * SEQ;

    const int q0 = my_qt * 64 + wq * 16;
    const bf16x8 aq0 = *(const bf16x8*)(Qb + (size_t)(q0 + l16) * HD + quad * 8);
    const bf16x8 aq1 = *(const bf16x8*)(Qb + (size_t)(q0 + l16) * HD + 32 + quad * 8);

    // staging: 512 threads, one b128 each for K and V
    const int srow = tid >> 3, scol = (tid & 7) * 8;
    const int lds_off = srow * FA_PAD + scol;

    f32x4 o[4];
    #pragma unroll
    for (int i = 0; i < 4; i++) o[i] = (f32x4){0.f, 0.f, 0.f, 0.f};
    float lsum = 0.f;

    // prologue: tile 0 -> buf 0
    bf16x8 pK = *(const bf16x8*)(Kb + (size_t)srow * HD + scol);
    bf16x8 pV = *(const bf16x8*)(Vb + (size_t)srow * SEQ + scol);
    *(bf16x8*)&Ks[0][lds_off] = pK;
    *(bf16x8*)&Vs[0][lds_off] = pV;

    for (int kt = 0; kt < niter; ++kt) {
        const int cur = kt & 1;
        // prefetch next tile before the barrier (spans barrier-wait + compute)
        if (kt + 1 < niter) {
            const int kn = (kt + 1) * 64;
            pK = *(const bf16x8*)(Kb + (size_t)(kn + srow) * HD + scol);
            pV = *(const bf16x8*)(Vb + (size_t)srow * SEQ + kn + scol);
        }
        __syncthreads();   // buf[cur] visible; everyone done reading buf[cur^1]

        if (kt <= my_qt) {
            const bool diag = (kt == my_qt);
            const bf16_t* KsC = &Ks[cur][0];
            const bf16_t* VsC = &Vs[cur][0];

            #pragma unroll
            for (int ni = 0; ni < 4; ni++) {
                if (diag && ni > wq) {   // fully-masked kv sub-tile
                    *(bf16x4*)&pT[w][l16][ni * 16 + quad * 4] = (bf16x4){0, 0, 0, 0};
                    continue;
                }
                bf16x8 kb0 = *(const bf16x8*)&KsC[(ni * 16 + l16) * FA_PAD + quad * 8];
                bf16x8 kb1 = *(const bf16x8*)&KsC[(ni * 16 + l16) * FA_PAD + 32 + quad * 8];
                f32x4 t = (f32x4){0.f, 0.f, 0.f, 0.f};
                t = __builtin_amdgcn_mfma_f32_16x16x32_bf16(kb0, aq0, t, 0, 0, 0);  // S^T
                t = __builtin_amdgcn_mfma_f32_16x16x32_bf16(kb1, aq1, t, 0, 0, 0);
                bf16x4 pk;
                #pragma unroll
                for (int r = 0; r < 4; r++) {
                    float pv = exp2f(t[r] * SCALE_LOG2E);
                    if (diag && (ni * 16 + quad * 4 + r > wq * 16 + l16)) pv = 0.f;
                    lsum += pv;
                    pk[r] = (bf16_t)pv;
                }
                *(bf16x4*)&pT[w][l16][ni * 16 + quad * 4] = pk;
            }

            // PV: pT is wave-private -> no barrier
            #pragma unroll
            for (int ks = 0; ks < 2; ks++) {
                if (diag && wq * 16 + 15 < ks * 32) continue;
                bf16x8 ap = *(const bf16x8*)&pT[w][l16][ks * 32 + quad * 8];
                #pragma unroll
                for (int ni = 0; ni < 4; ni++) {
                    bf16x8 vb = *(const bf16x8*)&VsC[(ni * 16 + l16) * FA_PAD + ks * 32 + quad * 8];
                    o[ni] = __builtin_amdgcn_mfma_f32_16x16x32_bf16(ap, vb, o[ni], 0, 0, 0);
                }
            }
        }

        if (kt + 1 < niter) {
            *(bf16x8*)&Ks[cur ^ 1][lds_off] = pK;
            *(bf16x8*)&Vs[cur ^ 1][lds_off] = pV;
        }
    }

    // finalize: reduce lsum over quads, redistribute to C-layout rows
    lsum += __shfl_xor(lsum, 16);
    lsum += __shfl_xor(lsum, 32);
    f32x4 linv;
    #pragma unroll
    for (int r = 0; r < 4; r++)
        linv[r] = 1.0f / __shfl(lsum, quad * 4 + r);

    const int b = bh >> 4, h = bh & 15;
    #pragma unroll
    for (int ni = 0; ni < 4; ni++) {
        #pragma unroll
        for (int r = 0; r < 4; r++) {
            const size_t row = (size_t)b * SEQ + q0 + quad * 4 + r;
            AO[row * D_MODEL + h * HD + ni * 16 + l16] = (bf16_t)(o[ni][r] * linv[r]);
        }
    }
}

// ---------------- launcher ----------------
extern "C" void kernel_launch(void* const* d_in, const int* in_sizes, int n_in,
                              void* d_out, int out_size, void* d_ws, size_t ws_size,
                              hipStream_t stream) {
    const float* x     = (const float*)d_in[0];
    const float* w_qkv = (const float*)d_in[1];
    const float* w_o   = (const float*)d_in[2];
    const int*   tpos  = (const int*)d_in[3];
    float*       out   = (float*)d_out;

    char* ws = (char*)d_ws;
    bf16_t* xb  = (bf16_t*)(ws);                 //  8 MB
    bf16_t* wqb = (bf16_t*)(ws + 8388608);       //  6 MB
    bf16_t* wob = (bf16_t*)(ws + 14680064);      //  2 MB
    bf16_t* Qh  = (bf16_t*)(ws + 41943040);      //  8 MB: Q heads rope  [32,2048,64]
    bf16_t* Kh  = (bf16_t*)(ws + 50331648);      //  8 MB: K heads rope  [32,2048,64]
    bf16_t* VT  = (bf16_t*)(ws + 58720256);      //  8 MB: V^T           [32,64,2048]
    bf16_t* AO  = (bf16_t*)(ws + 67108864);      //  8 MB: attn out      [4096,1024]

    cvt_all<<<8192, 256, 0, stream>>>(x, w_qkv, w_o, xb, wqb, wob);

    // qkv GEMM with fused RoPE/head-split/V-transpose epilogue (LDS-staged writes)
    gemm_qkv_rope<<<dim3(32, 24), 256, 0, stream>>>(xb, wqb, tpos, Qh, Kh, VT);

    flash_attn<<<512, 512, 0, stream>>>(Qh, Kh, VT, AO);

    // out = AO @ w_o^T : M=4096, N=1024, K=1024 (fp32 out)
    gemm_nt<float, 2><<<dim3(32, 16), 256, 0, stream>>>(AO, wob, out, MROWS, D_MODEL, D_MODEL);
}